// Round 6
// baseline (220.180 us; speedup 1.0000x reference)
//
#include <hip/hip_runtime.h>
#include <hip/hip_bf16.h>
#include <stdint.h>

#define H 256
#define BT 4096
#define TS 128
#define ROWS 16
#define NBLK 256   // BT/ROWS, 1 block per CU
#define NTH 1024   // 16 waves, 4/SIMD
#define LD 260     // padded row (floats)

typedef __attribute__((ext_vector_type(8))) short bf16x8;
typedef __attribute__((ext_vector_type(4))) float f32x4;

__device__ __forceinline__ float exp2_fast(float x){ float r; asm("v_exp_f32 %0, %1" : "=v"(r) : "v"(x)); return r; }
__device__ __forceinline__ float rcp_fast(float x){ float r; asm("v_rcp_f32 %0, %1" : "=v"(r) : "v"(x)); return r; }
__device__ __forceinline__ float rsq_fast(float x){ float r; asm("v_rsq_f32 %0, %1" : "=v"(r) : "v"(x)); return r; }
__device__ __forceinline__ float tanh_fast(float x){
  float e = exp2_fast(x * 2.8853900817779268f);
  return 1.0f - 2.0f * rcp_fast(e + 1.0f);
}
__device__ __forceinline__ unsigned short bf16_rne(float f){   // init-time only
  unsigned u = __float_as_uint(f);
  u += 0x7fffu + ((u >> 16) & 1u);
  return (unsigned short)(u >> 16);
}
__device__ __forceinline__ float bf16f(unsigned short h){ return __uint_as_float(((unsigned)h) << 16); }
// packed RNE f32->bf16 pair (v_cvt_pk_bf16_f32), same rounding as bf16_rne
__device__ __forceinline__ unsigned pk_bf16(float a, float b){
  __hip_bfloat162 h2 = __float22bfloat162_rn(make_float2(a, b));
  union { __hip_bfloat162 h; unsigned u; } cv; cv.h = h2; return cv.u;   // a in low 16
}
// barrier w/o vmcnt drain: cross-wave deps are LDS-only; hist ld/st are same-wave, 61+ steps apart
__device__ __forceinline__ void bar_lgkm(){ asm volatile("s_waitcnt lgkmcnt(0)\n\ts_barrier" ::: "memory"); }

// VALU-pipe cross-lane add via DPP
template<int CTRL>
__device__ __forceinline__ float dpp_add(float x){
  int y = __builtin_amdgcn_update_dpp(0, __float_as_int(x), CTRL, 0xf, 0xf, false);
  return x + __int_as_float(y);
}
#define ROR1 0x121
#define ROR2 0x122
#define ROR4 0x124
#define ROR8 0x128
#define BC15 0x142   // row_bcast15: lanes 16-31 <- l15, lanes 48-63 <- l47
#define BC31 0x143   // row_bcast31: lanes 32-63 <- l31
__device__ __forceinline__ float lane_f(float v, int n){
  return __int_as_float(__builtin_amdgcn_readlane(__float_as_int(v), n));
}

__global__ __launch_bounds__(NTH, 4) void wp_kernel(
    const float* __restrict__ x, const float* __restrict__ We, const float* __restrict__ be,
    const float* __restrict__ Wu, const float* __restrict__ bu, const float* __restrict__ gm,
    const float* __restrict__ bt, const float* __restrict__ Wo, const float* __restrict__ bo,
    const float* __restrict__ cst, unsigned short* __restrict__ hist, float* __restrict__ out,
    int use_hist)
{
  __shared__ __align__(16) float emb[10][LD];
  __shared__ __align__(16) float hpre[ROWS][LD];
  // A frags: element k=32kc+8fo'+4e'+j of row r in plane kc, physical row (r+16fo')^kc^(2fo').
  // Reads b128 + writes b64 conflict-free (HW-verified r4/r5: SQ_LDS_BANK_CONFLICT=0)
  __shared__ __align__(16) unsigned short afrag[8][64][8];
  // K-split partial exchange: lane-linear b128 slots (same verified shape: byte = l*16)
  __shared__ __align__(16) float xpart[8][2][64][4];
  __shared__ unsigned char xidx[ROWS][TS];

  const int tid = threadIdx.x;
  const int r0 = blockIdx.x * ROWS;
  const int w  = tid >> 6;        // wave 0..15
  const int l  = tid & 63;
  const int fr = l & 15;
  const int fo = l >> 4;
  const int kh = w >> 3;          // K-half: k in [128*kh, 128*kh+128)
  const int n  = w & 7;           // col-pair tile: cols [32n, 32n+32)
  const int kcbase = 4*kh;
  const int c0 = 32*n + fr, c1 = c0 + 16;

  float cs;
  { float c = cst[0]; cs = rcp_fast(1.0f + exp2_fast(-c * 1.4426950408889634f)); }

  for (int i = tid; i < ROWS*TS; i += NTH) {
    int r = i >> 7, t = i & 127;
    xidx[r][t] = (unsigned char)(int)(x[((size_t)(r0 + r))*TS + t] + 0.5f);
  }
  for (int i = tid; i < 10*H; i += NTH) {
    int v = i >> 8, k = i & 255;
    emb[v][k] = tanh_fast((float)v * We[k] + be[k]);
  }

  // W_update hi+lo bf16 frags for this wave's K-half and col pair (64 regs)
  bf16x8 whi0[4], wlo0[4], whi1[4], wlo1[4];
  #pragma unroll
  for (int kc = 0; kc < 4; ++kc) {
    #pragma unroll
    for (int i = 0; i < 8; ++i) {
      int kg = 128*kh + 32*kc + 8*fo + i;
      float w0 = Wu[(size_t)kg*H + c0];
      float w1 = Wu[(size_t)kg*H + c1];
      unsigned short h0 = bf16_rne(w0), h1 = bf16_rne(w1);
      whi0[kc][i] = (short)h0; wlo0[kc][i] = (short)bf16_rne(w0 - bf16f(h0));
      whi1[kc][i] = (short)h1; wlo1[kc][i] = (short)bf16_rne(w1 - bf16f(h1));
    }
  }
  const float bval = bu[kh ? c1 : c0];
  f32x4 g4 = *(const f32x4*)(gm + 4*l);
  f32x4 b4 = *(const f32x4*)(bt + 4*l);

  // per-thread-constant addresses (loop-invariant)
  const int XR = l ^ (2*fo);                    // phase2 read row base (^kc per plane)
  const int wkc = l >> 3, wfo = (l >> 1) & 3, we = l & 1;
  unsigned short* const aw = &afrag[wkc][(w + 16*wfo) ^ wkc ^ (2*wfo)][4*we];
  const float* const h4p = &hpre[w][4*l];
  float* const ffin = &hpre[w][4*l];
  const unsigned char* const xr = &xidx[w][0];
  const size_t histLane = (size_t)(r0 + w)*H + 4*l;
  __syncthreads();

  // prologue: A-frags for t=0 (h=0, no ctx)
  {
    int xv = xr[0];
    f32x4 e4 = *(const f32x4*)&emb[xv][4*l];
    uint2 p = { pk_bf16(e4[0], e4[1]), pk_bf16(e4[2], e4[3]) };
    *(uint2*)aw = p;
  }
  __syncthreads();

  uint2 cP = {0,0}, cQ = {0,0};

// phase 2: partial GEMM over this wave's K-half (2 chains of 8 MFMA), symmetric
// partial exchange (kh=0 exports c1-partial & finalizes c0; kh=1 exports c0 & finalizes c1)
#define PHASE2() do { \
    f32x4 acc0 = {0.f,0.f,0.f,0.f}, acc1 = {0.f,0.f,0.f,0.f}; \
    _Pragma("unroll") \
    for (int kc = 0; kc < 4; ++kc) { \
      bf16x8 af = *(const bf16x8*)&afrag[kcbase+kc][XR ^ (kcbase+kc)][0]; \
      acc0 = __builtin_amdgcn_mfma_f32_16x16x32_bf16(af, whi0[kc], acc0, 0, 0, 0); \
      acc0 = __builtin_amdgcn_mfma_f32_16x16x32_bf16(af, wlo0[kc], acc0, 0, 0, 0); \
      acc1 = __builtin_amdgcn_mfma_f32_16x16x32_bf16(af, whi1[kc], acc1, 0, 0, 0); \
      acc1 = __builtin_amdgcn_mfma_f32_16x16x32_bf16(af, wlo1[kc], acc1, 0, 0, 0); \
    } \
    if (kh == 0) { *(f32x4*)&xpart[n][1][l][0] = acc1; } \
    else         { *(f32x4*)&xpart[n][0][l][0] = acc0; } \
    bar_lgkm(); \
    if (kh == 0) { \
      f32x4 p = *(const f32x4*)&xpart[n][0][l][0]; \
      _Pragma("unroll") \
      for (int q = 0; q < 4; ++q) hpre[4*fo + q][c0] = tanh_fast(acc0[q] + p[q] + bval); \
    } else { \
      f32x4 p = *(const f32x4*)&xpart[n][1][l][0]; \
      _Pragma("unroll") \
      for (int q = 0; q < 4; ++q) hpre[4*fo + q][c1] = tanh_fast(acc1[q] + p[q] + bval); \
    } \
  } while(0)

// LN stats + normalized values from h4 (row-bcast final combine, total in lane 63)
#define LN_STATS_HV(h4) \
    float s1 = (h4[0]+h4[1]) + (h4[2]+h4[3]); \
    float s2 = h4[0]*h4[0]; \
    s2 = fmaf(h4[1],h4[1],s2); s2 = fmaf(h4[2],h4[2],s2); s2 = fmaf(h4[3],h4[3],s2); \
    s1 = dpp_add<ROR1>(s1); s1 = dpp_add<ROR2>(s1); s1 = dpp_add<ROR4>(s1); s1 = dpp_add<ROR8>(s1); \
    s2 = dpp_add<ROR1>(s2); s2 = dpp_add<ROR2>(s2); s2 = dpp_add<ROR4>(s2); s2 = dpp_add<ROR8>(s2); \
    s1 = dpp_add<BC15>(s1); s1 = dpp_add<BC31>(s1); \
    s2 = dpp_add<BC15>(s2); s2 = dpp_add<BC31>(s2); \
    float S1 = lane_f(s1, 63); \
    float S2 = lane_f(s2, 63); \
    float mu  = S1 * 0.00390625f; \
    float var = S2 * 0.00390625f - mu*mu; \
    float rs  = rsq_fast(var + 1e-5f); \
    float hv0 = fmaf(h4[0]-mu, rs*g4[0], b4[0]); \
    float hv1 = fmaf(h4[1]-mu, rs*g4[1], b4[1]); \
    float hv2 = fmaf(h4[2]-mu, rs*g4[2], b4[2]); \
    float hv3 = fmaf(h4[3]-mu, rs*g4[3], b4[3]);

#define PHASE3(HW, CUSE, CLOAD, tt) do { \
    f32x4 h4 = *(const f32x4*)h4p; \
    int xv = xr[(tt)+1]; \
    f32x4 e4 = *(const f32x4*)&emb[xv][4*l]; \
    LN_STATS_HV(h4); \
    if ((HW) && use_hist) { \
      uint2 hb = { pk_bf16(hv0,hv1), pk_bf16(hv2,hv3) }; \
      *(uint2*)(hist + (size_t)(tt)*(BT*H) + histLane) = hb; \
    } \
    float a0, a1, a2, a3; \
    if ((CUSE) && use_hist) { \
      a0 = fmaf(cs, __uint_as_float(cP.x << 16),         e4[0] + hv0); \
      a1 = fmaf(cs, __uint_as_float(cP.x & 0xffff0000u), e4[1] + hv1); \
      a2 = fmaf(cs, __uint_as_float(cP.y << 16),         e4[2] + hv2); \
      a3 = fmaf(cs, __uint_as_float(cP.y & 0xffff0000u), e4[3] + hv3); \
    } else { \
      a0 = e4[0] + hv0; a1 = e4[1] + hv1; a2 = e4[2] + hv2; a3 = e4[3] + hv3; \
    } \
    uint2 pkk = { pk_bf16(a0,a1), pk_bf16(a2,a3) }; \
    *(uint2*)aw = pkk; \
    if ((CUSE) || (CLOAD)) { cP = cQ; } \
    if ((CLOAD) && use_hist) \
      cQ = *(const uint2*)(hist + (size_t)((tt)-61)*(BT*H) + histLane); \
  } while(0)

  // segmented t-loop: all step-uniform branches resolved at compile time per segment
  for (int t = 0; t < 61; ++t)  { PHASE2(); bar_lgkm(); PHASE3(1,0,0,t); bar_lgkm(); }
  for (int t = 61; t < 63; ++t) { PHASE2(); bar_lgkm(); PHASE3(1,0,1,t); bar_lgkm(); }
  {                               PHASE2(); bar_lgkm(); PHASE3(1,1,1,63); bar_lgkm(); }
  for (int t = 64; t < 125; ++t){ PHASE2(); bar_lgkm(); PHASE3(0,1,1,t); bar_lgkm(); }
  for (int t = 125; t < 127; ++t){PHASE2(); bar_lgkm(); PHASE3(0,1,0,t); bar_lgkm(); }
  {                               // t = 127: final LN -> f32 row
    PHASE2(); bar_lgkm();
    f32x4 h4 = *(const f32x4*)h4p;
    LN_STATS_HV(h4);
    f32x4 o = {hv0, hv1, hv2, hv3};
    *(f32x4*)ffin = o;
  }

  __syncthreads();
  // final projection: out = h @ W_out + b_out  ([16,256]@[256,10] per block)
  if (tid < ROWS * 10) {
    int r = tid / 10, c = tid % 10;
    float acc = bo[c];
    for (int k = 0; k < H; ++k) acc += hpre[r][k] * Wo[k*10 + c];
    out[((size_t)(r0 + r))*10 + c] = acc;
  }
}

extern "C" void kernel_launch(void* const* d_in, const int* in_sizes, int n_in,
                              void* d_out, int out_size, void* d_ws, size_t ws_size,
                              hipStream_t stream) {
  const float* x   = (const float*)d_in[0];
  const float* We  = (const float*)d_in[1];
  const float* be  = (const float*)d_in[2];
  const float* Wu  = (const float*)d_in[3];
  const float* bu  = (const float*)d_in[4];
  const float* gm  = (const float*)d_in[5];
  const float* bt  = (const float*)d_in[6];
  const float* Wo  = (const float*)d_in[7];
  const float* bo  = (const float*)d_in[8];
  const float* cst = (const float*)d_in[9];
  float* out = (float*)d_out;

  size_t need = (size_t)64 * BT * H * sizeof(unsigned short); // 128 MB history ring
  int use_hist = (ws_size >= need) ? 1 : 0;

  hipLaunchKernelGGL(wp_kernel, dim3(NBLK), dim3(NTH), 0, stream,
                     x, We, be, Wu, bu, gm, bt, Wo, bo, cst,
                     (unsigned short*)d_ws, out, use_hist);
}

// Round 7
// 145.234 us; speedup vs baseline: 1.5160x; 1.5160x over previous
//
#include <hip/hip_runtime.h>
#include <hip/hip_bf16.h>
#include <hip/hip_fp16.h>
#include <stdint.h>

#define H 256
#define BT 4096
#define TS 128
#define ROWS 16
#define NBLK 256   // BT/ROWS, 1 block per CU
#define NTH 1024   // 16 waves, 4/SIMD
#define LD 260     // padded row (floats) for emb
#define LDP 264    // packed-hp row (u32), 2-way banks max (16fo pattern)

typedef __attribute__((ext_vector_type(8))) _Float16 f16x8;
typedef __attribute__((ext_vector_type(4))) float f32x4;

__device__ __forceinline__ float exp2_fast(float x){ float r; asm("v_exp_f32 %0, %1" : "=v"(r) : "v"(x)); return r; }
__device__ __forceinline__ float rcp_fast(float x){ float r; asm("v_rcp_f32 %0, %1" : "=v"(r) : "v"(x)); return r; }
__device__ __forceinline__ float rsq_fast(float x){ float r; asm("v_rsq_f32 %0, %1" : "=v"(r) : "v"(x)); return r; }
__device__ __forceinline__ float tanh_fast(float x){
  float e = exp2_fast(x * 2.8853900817779268f);
  return 1.0f - 2.0f * rcp_fast(e + 1.0f);
}
// f32 -> f16 low 16 bits of a cvt (RNE); used via packed pair below
__device__ __forceinline__ unsigned pk_f16(float a, float b){
  __half2 h2 = __float22half2_rn(make_float2(a, b));   // a in low 16
  union { __half2 h; unsigned u; } cv; cv.h = h2; return cv.u;
}
__device__ __forceinline__ float f16_lo_f32(unsigned v){   // cvt low 16 bits f16->f32
  float r; asm("v_cvt_f32_f16 %0, %1" : "=v"(r) : "v"(v)); return r;
}
// bf16 helpers (hist ring stays bf16, identical numerics to r1-r6)
__device__ __forceinline__ unsigned pk_bf16(float a, float b){
  __hip_bfloat162 h2 = __float22bfloat162_rn(make_float2(a, b));
  union { __hip_bfloat162 h; unsigned u; } cv; cv.h = h2; return cv.u;
}
// barrier w/o vmcnt drain: cross-wave deps are LDS-only; hist ld/st same-wave, 61+ steps apart
__device__ __forceinline__ void bar_lgkm(){ asm volatile("s_waitcnt lgkmcnt(0)\n\ts_barrier" ::: "memory"); }

template<int CTRL>
__device__ __forceinline__ float dpp_add(float x){
  int y = __builtin_amdgcn_update_dpp(0, __float_as_int(x), CTRL, 0xf, 0xf, false);
  return x + __int_as_float(y);
}
#define ROR1 0x121
#define ROR2 0x122
#define ROR4 0x124
#define ROR8 0x128
#define BC15 0x142
#define BC31 0x143
__device__ __forceinline__ float lane_f(float v, int n){
  return __int_as_float(__builtin_amdgcn_readlane(__float_as_int(v), n));
}

__global__ __launch_bounds__(NTH, 4) void wp_kernel(
    const float* __restrict__ x, const float* __restrict__ We, const float* __restrict__ be,
    const float* __restrict__ Wu, const float* __restrict__ bu, const float* __restrict__ gm,
    const float* __restrict__ bt, const float* __restrict__ Wo, const float* __restrict__ bo,
    const float* __restrict__ cst, unsigned short* __restrict__ hist, float* __restrict__ out,
    int use_hist)
{
  __shared__ __align__(16) float emb[10][LD];
  // h-pre-LN, f16 2-row packed: hp[rp][c] = (h[2rp][c] lo, h[2rp+1][c] hi)
  __shared__ __align__(16) unsigned hp[8][LDP];
  __shared__ __align__(16) float hfin[ROWS][LDP];   // final f32 h (t=127 only)
  // A frags (f16 now): element k=32kc+8fo'+4e'+j of row r in plane kc, physical row
  // (r+16fo')^kc^(2fo'). b128 reads + b64 writes conflict-free (HW-verified r4-r6: 0 conflicts)
  __shared__ __align__(16) unsigned short afrag[8][64][8];
  __shared__ unsigned char xidx[ROWS][TS];

  const int tid = threadIdx.x;
  const int r0 = blockIdx.x * ROWS;
  const int w  = tid >> 6;        // wave 0..15: N-cols [16w,16w+16) phase2; row w phase3
  const int l  = tid & 63;
  const int fr = l & 15;
  const int fo = l >> 4;
  const int c0 = 16*w + fr;       // phase2 D column
  const int rp = w >> 1;          // phase3 rowpair
  const int sh = (w & 1) << 4;    // phase3 sub-row shift within packed u32

  float cs;
  { float c = cst[0]; cs = rcp_fast(1.0f + exp2_fast(-c * 1.4426950408889634f)); }

  for (int i = tid; i < ROWS*TS; i += NTH) {
    int r = i >> 7, t = i & 127;
    xidx[r][t] = (unsigned char)(int)(x[((size_t)(r0 + r))*TS + t] + 0.5f);
  }
  for (int i = tid; i < 10*H; i += NTH) {
    int v = i >> 8, k = i & 255;
    emb[v][k] = tanh_fast((float)v * We[k] + be[k]);
  }

  // W_update f16 frags (32 regs): single-MFMA path (f16 precision replaces bf16 hi+lo)
  f16x8 wf[8];
  #pragma unroll
  for (int kc = 0; kc < 8; ++kc) {
    #pragma unroll
    for (int i = 0; i < 8; ++i) {
      int kg = 32*kc + 8*fo + i;
      wf[kc][i] = (_Float16)Wu[(size_t)kg*H + c0];   // RNE f32->f16
    }
  }
  const float bval = bu[c0];
  f32x4 g4 = *(const f32x4*)(gm + 4*l);
  f32x4 b4 = *(const f32x4*)(bt + 4*l);

  // per-thread-constant addresses (loop-invariant)
  const int XR = l ^ (2*fo);                    // phase2 afrag read row base (^kc per plane)
  const int wkc = l >> 3, wfo = (l >> 1) & 3, we = l & 1;
  unsigned short* const aw = &afrag[wkc][(w + 16*wfo) ^ wkc ^ (2*wfo)][4*we];
  const unsigned* const hpr = &hp[rp][4*l];
  const unsigned char* const xr = &xidx[w][0];
  const size_t histLane = (size_t)(r0 + w)*H + 4*l;
  __syncthreads();

  // prologue: A-frags for t=0 (h=0, no ctx)
  {
    int xv = xr[0];
    f32x4 e4 = *(const f32x4*)&emb[xv][4*l];
    uint2 p = { pk_f16(e4[0], e4[1]), pk_f16(e4[2], e4[3]) };
    *(uint2*)aw = p;
  }
  __syncthreads();

  uint2 cP = {0,0}, cQ = {0,0};

// phase 2: h_pre = tanh(A @ Wu + bu); bias pre-seeded in acc; f16 2-row-packed store
#define PHASE2() do { \
    f32x4 acc = {bval, bval, bval, bval}; \
    _Pragma("unroll") \
    for (int kc = 0; kc < 8; ++kc) { \
      f16x8 af = *(const f16x8*)&afrag[kc][XR ^ kc][0]; \
      acc = __builtin_amdgcn_mfma_f32_16x16x32_f16(af, wf[kc], acc, 0, 0, 0); \
    } \
    hp[2*fo  ][c0] = pk_f16(tanh_fast(acc[0]), tanh_fast(acc[1])); \
    hp[2*fo+1][c0] = pk_f16(tanh_fast(acc[2]), tanh_fast(acc[3])); \
  } while(0)

// LN stats + normalized values; h from packed-f16 hp (stats self-consistent on rounded h)
#define LN_STATS_HV() \
    uint4 qv = *(const uint4*)hpr; \
    float h0 = f16_lo_f32(qv.x >> sh); \
    float h1 = f16_lo_f32(qv.y >> sh); \
    float h2 = f16_lo_f32(qv.z >> sh); \
    float h3 = f16_lo_f32(qv.w >> sh); \
    float s1 = (h0+h1) + (h2+h3); \
    float s2 = h0*h0; \
    s2 = fmaf(h1,h1,s2); s2 = fmaf(h2,h2,s2); s2 = fmaf(h3,h3,s2); \
    s1 = dpp_add<ROR1>(s1); s1 = dpp_add<ROR2>(s1); s1 = dpp_add<ROR4>(s1); s1 = dpp_add<ROR8>(s1); \
    s2 = dpp_add<ROR1>(s2); s2 = dpp_add<ROR2>(s2); s2 = dpp_add<ROR4>(s2); s2 = dpp_add<ROR8>(s2); \
    s1 = dpp_add<BC15>(s1); s1 = dpp_add<BC31>(s1); \
    s2 = dpp_add<BC15>(s2); s2 = dpp_add<BC31>(s2); \
    float S1 = lane_f(s1, 63); \
    float S2 = lane_f(s2, 63); \
    float mu  = S1 * 0.00390625f; \
    float var = S2 * 0.00390625f - mu*mu; \
    float rs  = rsq_fast(var + 1e-5f); \
    float hv0 = fmaf(h0-mu, rs*g4[0], b4[0]); \
    float hv1 = fmaf(h1-mu, rs*g4[1], b4[1]); \
    float hv2 = fmaf(h2-mu, rs*g4[2], b4[2]); \
    float hv3 = fmaf(h3-mu, rs*g4[3], b4[3]);

#define PHASE3(HW, CUSE, CLOAD, tt) do { \
    int xv = xr[(tt)+1]; \
    f32x4 e4 = *(const f32x4*)&emb[xv][4*l]; \
    LN_STATS_HV(); \
    float a0, a1, a2, a3; \
    if ((CUSE) && use_hist) { \
      a0 = fmaf(cs, __uint_as_float(cP.x << 16),         e4[0] + hv0); \
      a1 = fmaf(cs, __uint_as_float(cP.x & 0xffff0000u), e4[1] + hv1); \
      a2 = fmaf(cs, __uint_as_float(cP.y << 16),         e4[2] + hv2); \
      a3 = fmaf(cs, __uint_as_float(cP.y & 0xffff0000u), e4[3] + hv3); \
    } else { \
      a0 = e4[0] + hv0; a1 = e4[1] + hv1; a2 = e4[2] + hv2; a3 = e4[3] + hv3; \
    } \
    uint2 pkk = { pk_f16(a0,a1), pk_f16(a2,a3) }; \
    *(uint2*)aw = pkk; \
    if ((HW) && use_hist) { \
      uint2 hb = { pk_bf16(hv0,hv1), pk_bf16(hv2,hv3) }; \
      *(uint2*)(hist + (size_t)(tt)*(BT*H) + histLane) = hb; \
    } \
    if ((CUSE) || (CLOAD)) { cP = cQ; } \
    if ((CLOAD) && use_hist) \
      cQ = *(const uint2*)(hist + (size_t)((tt)-61)*(BT*H) + histLane); \
  } while(0)

  // segmented t-loop: all step-uniform branches resolved at compile time per segment
  for (int t = 0; t < 61; ++t)  { PHASE2(); bar_lgkm(); PHASE3(1,0,0,t); bar_lgkm(); }
  for (int t = 61; t < 63; ++t) { PHASE2(); bar_lgkm(); PHASE3(1,0,1,t); bar_lgkm(); }
  {                               PHASE2(); bar_lgkm(); PHASE3(1,1,1,63); bar_lgkm(); }
  for (int t = 64; t < 125; ++t){ PHASE2(); bar_lgkm(); PHASE3(0,1,1,t); bar_lgkm(); }
  for (int t = 125; t < 127; ++t){PHASE2(); bar_lgkm(); PHASE3(0,1,0,t); bar_lgkm(); }
  {                               // t = 127: final LN -> f32 row for projection
    PHASE2(); bar_lgkm();
    LN_STATS_HV();
    f32x4 o = {hv0, hv1, hv2, hv3};
    *(f32x4*)&hfin[w][4*l] = o;
  }

  __syncthreads();
  // final projection: out = h @ W_out + b_out  ([16,256]@[256,10] per block)
  if (tid < ROWS * 10) {
    int r = tid / 10, c = tid % 10;
    float acc = bo[c];
    for (int k = 0; k < H; ++k) acc += hfin[r][k] * Wo[k*10 + c];
    out[((size_t)(r0 + r))*10 + c] = acc;
  }
}

extern "C" void kernel_launch(void* const* d_in, const int* in_sizes, int n_in,
                              void* d_out, int out_size, void* d_ws, size_t ws_size,
                              hipStream_t stream) {
  const float* x   = (const float*)d_in[0];
  const float* We  = (const float*)d_in[1];
  const float* be  = (const float*)d_in[2];
  const float* Wu  = (const float*)d_in[3];
  const float* bu  = (const float*)d_in[4];
  const float* gm  = (const float*)d_in[5];
  const float* bt  = (const float*)d_in[6];
  const float* Wo  = (const float*)d_in[7];
  const float* bo  = (const float*)d_in[8];
  const float* cst = (const float*)d_in[9];
  float* out = (float*)d_out;

  size_t need = (size_t)64 * BT * H * sizeof(unsigned short); // 128 MB history ring
  int use_hist = (ws_size >= need) ? 1 : 0;

  hipLaunchKernelGGL(wp_kernel, dim3(NBLK), dim3(NTH), 0, stream,
                     x, We, be, Wu, bu, gm, bt, Wo, bo, cst,
                     (unsigned short*)d_ws, out, use_hist);
}